// Round 6
// baseline (128.759 us; speedup 1.0000x reference)
//
#include <hip/hip_runtime.h>
#include <hip/hip_bf16.h>

#define N 8192
#define FIN 256
#define FOUT 128
#define ALPHA 0.2f

typedef unsigned short ushort_t;
typedef __attribute__((ext_vector_type(8))) short short8;
typedef __attribute__((ext_vector_type(4))) float f32x4;

#define GLOAD16(gp, lp)                                        \
  __builtin_amdgcn_global_load_lds(                            \
      (const __attribute__((address_space(1))) void*)(gp),     \
      (__attribute__((address_space(3))) void*)(lp), 16, 0, 0)

__device__ __forceinline__ ushort_t f2bf(float x) {
  __hip_bfloat16 b = __float2bfloat16(x);  // RNE
  return *reinterpret_cast<ushort_t*>(&b);
}

// ---------------- Kernel 1: h = X@W (fp32), s1 = h@a1, s2 = h@a2, hT = bf16(h)^T ----
__global__ __launch_bounds__(256) void k_h(const float* __restrict__ inp,
                                           const float* __restrict__ Wm,
                                           const float* __restrict__ av,
                                           ushort_t* __restrict__ hT,
                                           float* __restrict__ s1,
                                           float* __restrict__ s2) {
  __shared__ float in_lds[16][FIN];
  __shared__ float h_tile[16][FOUT];
  const int t = threadIdx.x;
  const int r0 = blockIdx.x * 16;

  for (int idx = t; idx < 16 * FIN; idx += 256) {
    int ii = idx >> 8, kk = idx & 255;
    in_lds[ii][kk] = inp[(size_t)(r0 + ii) * FIN + kk];
  }
  __syncthreads();

  const int c2 = (t & 63) * 2;
  const int rg = t >> 6;
  float acc[4][2] = {};
  for (int k = 0; k < FIN; k += 4) {
    float4 iv[4];
#pragma unroll
    for (int q = 0; q < 4; ++q)
      iv[q] = *reinterpret_cast<const float4*>(&in_lds[rg * 4 + q][k]);
#pragma unroll
    for (int kk = 0; kk < 4; ++kk) {
      float2 wp = *reinterpret_cast<const float2*>(&Wm[(size_t)(k + kk) * FOUT + c2]);
#pragma unroll
      for (int q = 0; q < 4; ++q) {
        float x = reinterpret_cast<const float*>(&iv[q])[kk];
        acc[q][0] = fmaf(x, wp.x, acc[q][0]);
        acc[q][1] = fmaf(x, wp.y, acc[q][1]);
      }
    }
  }
#pragma unroll
  for (int q = 0; q < 4; ++q) {
    h_tile[rg * 4 + q][c2] = acc[q][0];
    h_tile[rg * 4 + q][c2 + 1] = acc[q][1];
  }
  __syncthreads();

  const int wv_ = t >> 6, lane = t & 63;
#pragma unroll
  for (int rr = 0; rr < 4; ++rr) {
    int row = wv_ * 4 + rr;
    float h0 = h_tile[row][lane], h1 = h_tile[row][lane + 64];
    float p1 = h0 * av[lane] + h1 * av[lane + 64];
    float p2 = h0 * av[FOUT + lane] + h1 * av[FOUT + lane + 64];
#pragma unroll
    for (int m = 32; m; m >>= 1) {
      p1 += __shfl_xor(p1, m);
      p2 += __shfl_xor(p2, m);
    }
    if (lane == 0) { s1[r0 + row] = p1; s2[r0 + row] = p2; }
  }

  for (int idx = t; idx < 16 * FOUT; idx += 256) {
    int c = idx >> 4, ii = idx & 15;
    hT[(size_t)c * N + r0 + ii] = f2bf(h_tile[ii][c]);
  }
}

// ---------------- Kernel 1b: global max of s2 -------------------------------------
__global__ __launch_bounds__(256) void k_smax(const float* __restrict__ s2,
                                              float* __restrict__ outm) {
  __shared__ float red[4];
  const int t = threadIdx.x;
  float m = -1e30f;
  for (int i = t; i < N; i += 256) m = fmaxf(m, s2[i]);
#pragma unroll
  for (int d = 32; d; d >>= 1) m = fmaxf(m, __shfl_xor(m, d));
  if ((t & 63) == 0) red[t >> 6] = m;
  __syncthreads();
  if (t == 0) outm[0] = fmaxf(fmaxf(red[0], red[1]), fmaxf(red[2], red[3]));
}

// ---------------- Kernel 2: single-pass fused masked-softmax + P@h ----------------
// Grid 256 = 128 row-blocks x 2 chunks, 1 block/CU (135 KB LDS). Per 256-j tile:
//  - adj: each thread owns 32 consecutive j of one row (128 B contiguous, fully
//    coalesced block sweep), loaded ONE TILE AHEAD into regs, bitpacked to one
//    uint32, ds_written into a double-buffered 2 KB LDS mask. adj is the only
//    HBM stream (268 MB -> ~43 us floor).
//  - hT tile (64 KB) double-buffered via global_load_lds issued at top of the
//    compute phase for tile jt+1, consumed next tile. No per-tile stage drain.
//  - ONE barrier per tile.
__global__ __launch_bounds__(512) void k_attn(const int* __restrict__ adj,
                                              const ushort_t* __restrict__ hT,
                                              const float* __restrict__ s1g,
                                              const float* __restrict__ s2g,
                                              const float* __restrict__ s2max,
                                              float* __restrict__ slab,
                                              float* __restrict__ denp,
                                              int jc, int ntiles) {
  __shared__ __align__(16) ushort_t Bt[2][32768];     // 2 x 64 KB hT tile
  __shared__ unsigned mask_lds[2][64][8];             // 2 x 2 KB adjacency bits
  __shared__ float Dred[8][16];

  const int t = threadIdx.x;
  const int lane = t & 63;
  const int wid = t >> 6;
  const int rb = blockIdx.x & 127;
  const int chunk = blockIdx.x >> 7;
  const int i0 = rb * 64;
  const int jc0 = chunk * jc;

  const int g = wid & 3;        // row-group
  const int hf = wid >> 2;      // j-half of tile
  const int arow = lane & 15;   // A-frag row / B-frag col
  const int kb = lane >> 4;     // k-slot 0..3
  const int irow = i0 + g * 16 + arow;

  const float s1v = s1g[irow];
  const float mraw = s1v + s2max[0];
  const float mv = mraw > 0.f ? mraw : ALPHA * mraw;  // >= max_j e_ij (monotone)
  const float L2E = 1.44269504f;
  const float mvl = mv * L2E;

  // adj producer mapping: thread owns (row ar_, word aq) = 32 consecutive j
  const int ar_ = t >> 3, aq = t & 7;
  const int* __restrict__ adjq = adj + (size_t)(i0 + ar_) * N + jc0 + aq * 32;

  const float* __restrict__ s2p = s2g + jc0 + hf * 128 + kb * 8;
  const char* __restrict__ hTb = (const char*)hT;

#define STAGE_HT(J0, BUF)                                                          \
  _Pragma("unroll") for (int s = 0; s < 8; ++s) {                                  \
    int L = s * 512 + t;                                                           \
    int rr = L >> 5;                                                               \
    int boff = (L & 31) * 16;                                                      \
    const char* src =                                                              \
        hTb + ((size_t)rr * N + jc0 + (J0)) * 2 + (boff ^ ((rr & 7) << 4));        \
    GLOAD16(src, (char*)(&Bt[BUF][0]) + L * 16);                                   \
  }

#define LOAD_ADJ(J0)                                                               \
  _Pragma("unroll") for (int s = 0; s < 8; ++s)                                    \
      ar[s] = *reinterpret_cast<const int4*>(adjq + (J0) + s * 4);

#define PACK_MASK(BUF)                                                             \
  {                                                                                \
    unsigned w = 0;                                                                \
    _Pragma("unroll") for (int s = 0; s < 8; ++s) {                                \
      w |= (ar[s].x > 0 ? 1u : 0u) << (s * 4);                                     \
      w |= (ar[s].y > 0 ? 1u : 0u) << (s * 4 + 1);                                 \
      w |= (ar[s].z > 0 ? 1u : 0u) << (s * 4 + 2);                                 \
      w |= (ar[s].w > 0 ? 1u : 0u) << (s * 4 + 3);                                 \
    }                                                                              \
    mask_lds[BUF][ar_][aq] = w;                                                    \
  }

  f32x4 acc[8];
#pragma unroll
  for (int ct = 0; ct < 8; ++ct) acc[ct] = (f32x4){0.f, 0.f, 0.f, 0.f};
  float dacc = 0.f;
  int4 ar[8];

  // ---- prologue: tile 0 adj + hT ----
  LOAD_ADJ(0)
  STAGE_HT(0, 0)
  PACK_MASK(0)
  __syncthreads();  // mask[0] visible, Bt[0] staged (vmcnt+lgkm drained)

  for (int jt = 0; jt < ntiles; ++jt) {
    const int b = jt & 1;
    const bool pf = (jt + 1) < ntiles;

    // ---- prefetch tile jt+1: adj -> regs, hT -> Bt[b^1] (safe: all waves
    //      finished reading Bt[b^1] at the barrier ending tile jt-1) ----
    if (pf) {
      LOAD_ADJ((jt + 1) * 256)
      STAGE_HT((jt + 1) * 256, b ^ 1)
    }

    // ---- compute tile jt from Bt[b] + mask_lds[b] ----
    const char* btb = (const char*)(&Bt[b][0]);
    const unsigned* mrow = &mask_lds[b][g * 16 + arow][0];
#pragma unroll
    for (int kq = 0; kq < 4; ++kq) {
      short8 bf[8];
      const int byte0 = hf * 256 + kq * 64 + kb * 16;
#pragma unroll
      for (int ct = 0; ct < 8; ++ct) {
        int row = ct * 16 + arow;
        int off = row * 512 + (byte0 ^ ((row & 7) << 4));
        bf[ct] = *reinterpret_cast<const short8*>(btb + off);
      }
      const unsigned w8 = (mrow[hf * 4 + kq] >> (kb * 8)) & 0xffu;
      float4 sv0 = *reinterpret_cast<const float4*>(s2p + jt * 256 + kq * 32);
      float4 sv1 = *reinterpret_cast<const float4*>(s2p + jt * 256 + kq * 32 + 4);
      const float* sf0 = reinterpret_cast<const float*>(&sv0);
      const float* sf1 = reinterpret_cast<const float*>(&sv1);
      short8 af;
#pragma unroll
      for (int e = 0; e < 4; ++e) {
        float pre = s1v + sf0[e];
        float lr = fmaxf(pre, ALPHA * pre);
        float w = __builtin_amdgcn_exp2f(fmaf(lr, L2E, -mvl));
        w = ((w8 >> e) & 1u) ? w : 0.f;
        dacc += w;
        af[e] = (short)f2bf(w);
      }
#pragma unroll
      for (int e = 0; e < 4; ++e) {
        float pre = s1v + sf1[e];
        float lr = fmaxf(pre, ALPHA * pre);
        float w = __builtin_amdgcn_exp2f(fmaf(lr, L2E, -mvl));
        w = ((w8 >> (4 + e)) & 1u) ? w : 0.f;
        dacc += w;
        af[4 + e] = (short)f2bf(w);
      }
#pragma unroll
      for (int ct = 0; ct < 8; ++ct)
        acc[ct] = __builtin_amdgcn_mfma_f32_16x16x32_bf16(af, bf[ct], acc[ct], 0, 0, 0);
    }

    // ---- bitpack next tile's adj (loaded a full compute-phase ago) ----
    if (pf) PACK_MASK(b ^ 1)

    __syncthreads();  // one barrier per tile
  }
#undef STAGE_HT
#undef LOAD_ADJ
#undef PACK_MASK

  // ---- denominator partials: lanes {r, r+16, r+32, r+48} share row r ----
  dacc += __shfl_xor(dacc, 16);
  dacc += __shfl_xor(dacc, 32);
  if (lane < 16) Dred[wid][lane] = dacc;

  // ---- combine the two hf-halves' k-partials in LDS (reuse Bt) ----
  float (*Hred)[132] = (float(*)[132])(void*)Bt;  // 64 x 132 x 4B
  // C/D layout (m89-verified): col = ct*16 + arow, row-in-group = kb*4 + r
  if (hf == 0) {
#pragma unroll
    for (int ct = 0; ct < 8; ++ct)
#pragma unroll
      for (int r = 0; r < 4; ++r)
        Hred[g * 16 + kb * 4 + r][ct * 16 + arow] = acc[ct][r];
  }
  __syncthreads();
  if (hf == 1) {
#pragma unroll
    for (int ct = 0; ct < 8; ++ct)
#pragma unroll
      for (int r = 0; r < 4; ++r)
        Hred[g * 16 + kb * 4 + r][ct * 16 + arow] += acc[ct][r];
  }
  __syncthreads();

  if (t < 64)
    denp[(size_t)chunk * N + i0 + t] = Dred[t >> 4][t & 15] + Dred[(t >> 4) + 4][t & 15];

  for (int idx = t; idx < 64 * 128; idx += 512) {
    int r = idx >> 7, c = idx & 127;
    slab[((size_t)chunk * N + i0 + r) * 128 + c] = Hred[r][c];
  }
}

// ---------------- Kernel 3: combine chunks, divide, ELU ---------------------------
__global__ __launch_bounds__(256) void k_fin(const float* __restrict__ slab,
                                             const float* __restrict__ denp,
                                             float* __restrict__ out, int nchunks) {
  const int idx = blockIdx.x * 256 + threadIdx.x;  // < N*FOUT
  const int i = idx >> 7;
  float den = 0.f, v = 0.f;
  for (int k = 0; k < nchunks; ++k) {
    den += denp[(size_t)k * N + i];
    v += slab[(size_t)k * N * FOUT + idx];
  }
  v /= den;
  out[idx] = v > 0.f ? v : (__expf(v) - 1.f);
}

extern "C" void kernel_launch(void* const* d_in, const int* in_sizes, int n_in,
                              void* d_out, int out_size, void* d_ws, size_t ws_size,
                              hipStream_t stream) {
  const float* inp = (const float*)d_in[0];   // [N][FIN] fp32
  const int* adj   = (const int*)d_in[1];     // [N][N] int32
  const float* Wm  = (const float*)d_in[2];   // [FIN][FOUT] fp32
  const float* av  = (const float*)d_in[3];   // [2*FOUT] fp32
  float* out = (float*)d_out;

  // workspace carve-up (~10.5 MB total)
  char* ws = (char*)d_ws;
  ushort_t* hT = (ushort_t*)ws;                               // 2 MB
  float* s1    = (float*)(ws + (size_t)FOUT * N * 2);         // 32 KB
  float* s2    = s1 + N;                                      // 32 KB
  float* s2mx  = s2 + N;                                      // 16 B (padded)
  float* slab  = s2mx + 4;

  const int nchunks = 2;                                      // jc = 4096
  float* denp = slab + (size_t)nchunks * N * FOUT;
  const int jc = N / nchunks;
  const int ntiles = jc / 256;                                // 16

  k_h<<<N / 16, 256, 0, stream>>>(inp, Wm, av, hT, s1, s2);
  k_smax<<<1, 256, 0, stream>>>(s2, s2mx);
  k_attn<<<128 * nchunks, 512, 0, stream>>>(adj, hT, s1, s2, s2mx, slab, denp, jc, ntiles);
  k_fin<<<(N * FOUT) / 256, 256, 0, stream>>>(slab, denp, out, nchunks);
}